// Round 5
// baseline (783.001 us; speedup 1.0000x reference)
//
#include <hip/hip_runtime.h>
#include <hip/hip_bf16.h>

// GAT layer, B=8 N=4096 F=128 U=64, ALL I/O float32.
// out = relu( softmax_row( lrelu(s_i + t_j) masked by A ) @ X ),  X = H@W.
// R9: attn measured ~336us across ALL prior structures = 1.56 TB/s on the
// 512 MB A stream (vs 6.4 TB/s harness fill). Theory: 2D tile walk reads A
// as 256B pieces at 16KB row stride -> HBM channel/page aliasing. Fix: each
// row-visit is a dense 2KB sequential burst. Blocks own 32 rows; K-chunks of
// 512; each wave stages 4 rows (2KB contiguous each), computes w=exp2*mask
// inline, writes bf16 to dbuf LDS Ws[2][32][520] (66.6KB -> 2 blocks/CU).
// PV: 8 waves = 2 row-groups x 4 K-quarters; A-frag from LDS, XT B-frag from
// L2 (batch-per-XCD resident). One barrier per chunk.

#define NTOK 4096
#define FDIM 128
#define UDIM 64
#define BATCH 8
#define CK 512
#define NCH (NTOK / CK)

typedef __attribute__((ext_vector_type(8))) short short8;
typedef __attribute__((ext_vector_type(4))) float f32x4;

union PackU { unsigned u[4]; short8 s; };

// round-to-nearest-even f32 -> bf16 (used in prep only)
__device__ __forceinline__ unsigned short f2bf(float x) {
    unsigned u = __float_as_uint(x);
    return (unsigned short)((u + 0x7fffu + ((u >> 16) & 1u)) >> 16);
}

// ---------------- kernel 1: X = H@W (MFMA), s,t (pre-scaled by log2e) ------
__global__ __launch_bounds__(256) void prep_kernel(
    const float* __restrict__ H,    // f32 [B*N, 128]
    const float* __restrict__ W,    // f32 [128, 64]
    const float* __restrict__ a1,   // f32 [64]
    const float* __restrict__ a2,   // f32 [64]
    unsigned short* __restrict__ XT,// bf16 [B, 64, N] (scratch)
    float* __restrict__ s_out,      // f32 [B*N], = (X@a1)*log2(e)
    float* __restrict__ t_out)      // f32 [B*N], = (X@a2)*log2(e)
{
    __shared__ float Xl[4][16][UDIM + 1];

    const int tid  = threadIdx.x;
    const int wave = tid >> 6, lane = tid & 63;
    const int col  = lane & 15, quad = lane >> 4;
    const int i0   = (blockIdx.x * 4 + wave) * 16;

    f32x4 acc0 = {0,0,0,0}, acc1 = {0,0,0,0}, acc2 = {0,0,0,0}, acc3 = {0,0,0,0};
    const float* hrow = H + (size_t)(i0 + col) * FDIM + quad * 8;

    #pragma unroll
    for (int kb = 0; kb < FDIM; kb += 32) {
        f32x4 h0 = *(const f32x4*)(hrow + kb);       // A[m=lane&15][k=quad*8+j]
        f32x4 h1 = *(const f32x4*)(hrow + kb + 4);
        short8 afr, b0, b1, b2, b3;
        #pragma unroll
        for (int j = 0; j < 4; ++j) {
            afr[j]     = (short)f2bf(h0[j]);
            afr[4 + j] = (short)f2bf(h1[j]);
        }
        #pragma unroll
        for (int j = 0; j < 8; ++j) {                // W tiny, L1-hot
            int k = kb + quad * 8 + j;
            b0[j] = (short)f2bf(W[k * UDIM + col]);
            b1[j] = (short)f2bf(W[k * UDIM + 16 + col]);
            b2[j] = (short)f2bf(W[k * UDIM + 32 + col]);
            b3[j] = (short)f2bf(W[k * UDIM + 48 + col]);
        }
        acc0 = __builtin_amdgcn_mfma_f32_16x16x32_bf16(afr, b0, acc0, 0, 0, 0);
        acc1 = __builtin_amdgcn_mfma_f32_16x16x32_bf16(afr, b1, acc1, 0, 0, 0);
        acc2 = __builtin_amdgcn_mfma_f32_16x16x32_bf16(afr, b2, acc2, 0, 0, 0);
        acc3 = __builtin_amdgcn_mfma_f32_16x16x32_bf16(afr, b3, acc3, 0, 0, 0);
    }
    #pragma unroll
    for (int r = 0; r < 4; ++r) {   // C/D: col(u)=lane&15 (+16/group), row=quad*4+r
        Xl[wave][quad * 4 + r][col]      = acc0[r];
        Xl[wave][quad * 4 + r][16 + col] = acc1[r];
        Xl[wave][quad * 4 + r][32 + col] = acc2[r];
        Xl[wave][quad * 4 + r][48 + col] = acc3[r];
    }
    __syncthreads();

    const int b = i0 >> 12, n0 = i0 & (NTOK - 1);
    float ps = 0.f, pt = 0.f;
    #pragma unroll
    for (int ui = 0; ui < 16; ++ui) {
        int u = quad * 16 + ui;
        float x = Xl[wave][col][u];
        ps = fmaf(x, a1[u], ps);
        pt = fmaf(x, a2[u], pt);
    }
    ps += __shfl_xor(ps, 16, 64); ps += __shfl_xor(ps, 32, 64);
    pt += __shfl_xor(pt, 16, 64); pt += __shfl_xor(pt, 32, 64);
    const float LOG2E = 1.44269504f;
    if (quad == 0) s_out[i0 + col] = ps * LOG2E;   // exp2 domain
    if (quad == 1) t_out[i0 + col] = pt * LOG2E;

    #pragma unroll
    for (int ui = 0; ui < 16; ++ui) {
        int u = quad * 16 + ui;
        XT[(size_t)(b * UDIM + u) * NTOK + n0 + col] = f2bf(Xl[wave][col][u]);
    }
}

// ---------------- kernel 2: fused mask+softmax+PV ---------------------------
// grid 1024 = 8 batches x 128 row-tiles-of-32 (b = bx&7 keeps batch->XCD
// affinity for XT L2 residency). 8 waves of 64.
// Stage role: wave w owns rows w*4..w*4+3; per chunk reads 2KB/row dense.
// PV role: wave w -> row-group g=w&1 (16 rows), K-quarter h=w>>1 (128 of 512).
__global__ __launch_bounds__(512, 4) void attn_kernel(
    const float* __restrict__ A,            // f32 [B, N, N] -- 512 MB stream
    const unsigned short* __restrict__ XT,  // bf16 [B, 64, N]
    const float* __restrict__ s_in,         // log2e-scaled
    const float* __restrict__ t_in,         // log2e-scaled
    float* __restrict__ out)                // f32 [B, N, 64]
{
    __shared__ __align__(16) unsigned short Ws[2][32][CK + 8];  // 66.6 KB
    __shared__ float denl[32];

    const int tid  = threadIdx.x;
    const int wave = tid >> 6, lane = tid & 63;
    const int col  = lane & 15, quad = lane >> 4;
    const int b    = blockIdx.x & 7;
    const int i0   = (blockIdx.x >> 3) * 32;

    const int g = wave & 1, h = wave >> 1;   // PV role
    const int r0 = wave * 4;                 // stage rows (block-local)

    // stage pointers: lane covers k = lane*8 .. lane*8+7 of each 2KB row-chunk
    const float* ab = A + ((size_t)(b * NTOK + i0 + r0)) * NTOK + lane * 8;
    const float* tb = t_in + b * NTOK + lane * 8;
    float s_r[4];
    #pragma unroll
    for (int rr = 0; rr < 4; ++rr) s_r[rr] = s_in[b * NTOK + i0 + r0 + rr];

    // PV pointers (XT B-frags, L2-hot)
    const unsigned short* xp[4];
    #pragma unroll
    for (int f = 0; f < 4; ++f)
        xp[f] = XT + ((size_t)(b * UDIM + f * 16 + col)) * NTOK + h * 128 + quad * 8;

    f32x4 acc[4];
    #pragma unroll
    for (int f = 0; f < 4; ++f) acc[f] = (f32x4){0,0,0,0};
    float den_a[4] = {0.f, 0.f, 0.f, 0.f};

    f32x4 av0[4], av1[4], tv0, tv1;

    #define SLOAD(cc) do {                                                         \
        tv0 = *(const f32x4*)(tb + (cc) * CK);                                     \
        tv1 = *(const f32x4*)(tb + (cc) * CK + 4);                                 \
        _Pragma("unroll")                                                          \
        for (int rr = 0; rr < 4; ++rr) {                                           \
            av0[rr] = __builtin_nontemporal_load(                                  \
                (const f32x4*)(ab + (size_t)rr * NTOK + (cc) * CK));               \
            av1[rr] = __builtin_nontemporal_load(                                  \
                (const f32x4*)(ab + (size_t)rr * NTOK + (cc) * CK + 4));           \
        }                                                                          \
    } while (0)

    #define SWRITE(bufi) do {                                                      \
        _Pragma("unroll")                                                          \
        for (int rr = 0; rr < 4; ++rr) {                                           \
            unsigned uw[8];                                                        \
            float ds = 0.f;                                                        \
            _Pragma("unroll")                                                      \
            for (int j = 0; j < 4; ++j) {                                          \
                float l0 = s_r[rr] + tv0[j], l1 = s_r[rr] + tv1[j];                \
                float e0 = fmaxf(l0, 0.2f * l0);   /* lrelu, log2e>0 */            \
                float e1 = fmaxf(l1, 0.2f * l1);                                   \
                float w0 = __builtin_amdgcn_exp2f(e0) * av0[rr][j];                \
                float w1 = __builtin_amdgcn_exp2f(e1) * av1[rr][j];                \
                ds += w0 + w1;                                                     \
                uw[j]     = __float_as_uint(w0) + 0x8000u;                         \
                uw[4 + j] = __float_as_uint(w1) + 0x8000u;                         \
            }                                                                      \
            den_a[rr] += ds;                                                       \
            PackU p;                                                               \
            p.u[0] = __builtin_amdgcn_perm(uw[1], uw[0], 0x07060302u);             \
            p.u[1] = __builtin_amdgcn_perm(uw[3], uw[2], 0x07060302u);             \
            p.u[2] = __builtin_amdgcn_perm(uw[5], uw[4], 0x07060302u);             \
            p.u[3] = __builtin_amdgcn_perm(uw[7], uw[6], 0x07060302u);             \
            *(short8*)&Ws[bufi][r0 + rr][lane * 8] = p.s;                          \
        }                                                                          \
    } while (0)

    // prologue: chunk 0
    SLOAD(0);
    SWRITE(0);
    __syncthreads();

    for (int c = 0; c < NCH; ++c) {
        const int buf = c & 1;
        if (c + 1 < NCH) SLOAD(c + 1);     // dense 2KB/row bursts, land under PV

        // ---- PV(chunk c) ----
        const unsigned short* wrow = &Ws[buf][g * 16 + col][h * 128 + quad * 8];
        #pragma unroll
        for (int ks = 0; ks < 4; ++ks) {
            short8 af = *(const short8*)(wrow + ks * 32);
            short8 b0 = *(const short8*)(xp[0] + c * CK + ks * 32);
            short8 b1 = *(const short8*)(xp[1] + c * CK + ks * 32);
            short8 b2 = *(const short8*)(xp[2] + c * CK + ks * 32);
            short8 b3 = *(const short8*)(xp[3] + c * CK + ks * 32);
            acc[0] = __builtin_amdgcn_mfma_f32_16x16x32_bf16(af, b0, acc[0], 0, 0, 0);
            acc[1] = __builtin_amdgcn_mfma_f32_16x16x32_bf16(af, b1, acc[1], 0, 0, 0);
            acc[2] = __builtin_amdgcn_mfma_f32_16x16x32_bf16(af, b2, acc[2], 0, 0, 0);
            acc[3] = __builtin_amdgcn_mfma_f32_16x16x32_bf16(af, b3, acc[3], 0, 0, 0);
        }

        if (c + 1 < NCH) SWRITE(buf ^ 1);  // waits its loads; other waves overlap
        __syncthreads();
    }
    #undef SLOAD
    #undef SWRITE

    // ---- epilogue ----
    // den: full-row sums (each row staged entirely by one wave)
    #pragma unroll
    for (int rr = 0; rr < 4; ++rr) {
        float v = den_a[rr];
        v += __shfl_xor(v, 1, 64);  v += __shfl_xor(v, 2, 64);
        v += __shfl_xor(v, 4, 64);  v += __shfl_xor(v, 8, 64);
        v += __shfl_xor(v, 16, 64); v += __shfl_xor(v, 32, 64);
        if (lane == 0) denl[r0 + rr] = v;
    }
    __syncthreads();

    // K-quarter reduction via LDS (alias Ws -- all PV reads completed)
    float* red = (float*)&Ws[0][0][0];     // [3][2][16][68] f32 = 26.1 KB
    if (h > 0) {
        #pragma unroll
        for (int f = 0; f < 4; ++f)
            #pragma unroll
            for (int r = 0; r < 4; ++r)
                red[(((h - 1) * 2 + g) * 16 + quad * 4 + r) * 68 + f * 16 + col] = acc[f][r];
    }
    __syncthreads();
    if (h == 0) {
        #pragma unroll
        for (int f = 0; f < 4; ++f)
            #pragma unroll
            for (int r = 0; r < 4; ++r) {
                const int rl = quad * 4 + r;
                float v = acc[f][r]
                        + red[((0 * 2 + g) * 16 + rl) * 68 + f * 16 + col]
                        + red[((1 * 2 + g) * 16 + rl) * 68 + f * 16 + col]
                        + red[((2 * 2 + g) * 16 + rl) * 68 + f * 16 + col];
                float dd = denl[g * 16 + rl];
                float o  = fmaxf(v / dd, 0.f);
                __builtin_nontemporal_store(
                    o, &out[(size_t)(b * NTOK + i0 + g * 16 + rl) * UDIM + f * 16 + col]);
            }
    }
}

extern "C" void kernel_launch(void* const* d_in, const int* in_sizes, int n_in,
                              void* d_out, int out_size, void* d_ws, size_t ws_size,
                              hipStream_t stream) {
    const float* H  = (const float*)d_in[0];
    const float* A  = (const float*)d_in[1];
    const float* W  = (const float*)d_in[2];
    const float* a1 = (const float*)d_in[3];
    const float* a2 = (const float*)d_in[4];
    float* out = (float*)d_out;

    char* ws = (char*)d_ws;
    unsigned short* XT = (unsigned short*)ws;                               // 4 MB bf16
    size_t off = (size_t)BATCH * UDIM * NTOK * 2;
    float* s = (float*)(ws + off);                                          // 128 KB
    off += (size_t)BATCH * NTOK * 4;
    float* t = (float*)(ws + off);                                          // 128 KB

    prep_kernel<<<512, 256, 0, stream>>>(H, W, a1, a2, XT, s, t);
    attn_kernel<<<1024, 512, 0, stream>>>(A, XT, s, t, out);
}

// Round 6
// 699.734 us; speedup vs baseline: 1.1190x; 1.1190x over previous
//
#include <hip/hip_runtime.h>
#include <hip/hip_bf16.h>

// GAT layer, B=8 N=4096 F=128 U=64, ALL I/O float32.
// out = relu( softmax_row( lrelu(s_i + t_j) masked by A ) @ X ),  X = H@W.
// R10 = revert to R8/R6 (best measured: 702.4/707.4 us).
// Differential evidence across R4-R9 settles the cost model: attn is
// BW-bound near peak (~90us for the 512MB A stream; R5's 4x byte cut saved
// exactly the BW-predicted 52us; R9's serialization cost +81us). The other
// ~580us of dur_us is harness-side (one 2-GiB fill ~335us -- single
// Dispatch_Id residue class -- plus input re-poison). Controllable headroom
// ~20-25us (~3%), below fill noise. This is the roofline configuration.

#define NTOK 4096
#define FDIM 128
#define UDIM 64
#define BATCH 8
#define BK 64          // k-chunk staged per barrier (2 MFMA k-steps)

typedef __attribute__((ext_vector_type(8))) short short8;
typedef __attribute__((ext_vector_type(4))) float f32x4;

union PackU { unsigned u[4]; short8 s; };

// round-to-nearest-even f32 -> bf16 (used in prep only)
__device__ __forceinline__ unsigned short f2bf(float x) {
    unsigned u = __float_as_uint(x);
    return (unsigned short)((u + 0x7fffu + ((u >> 16) & 1u)) >> 16);
}

// ---------------- kernel 1: X = H@W (MFMA), s,t (pre-scaled by log2e) ------
__global__ __launch_bounds__(256) void prep_kernel(
    const float* __restrict__ H,    // f32 [B*N, 128]
    const float* __restrict__ W,    // f32 [128, 64]
    const float* __restrict__ a1,   // f32 [64]
    const float* __restrict__ a2,   // f32 [64]
    unsigned short* __restrict__ XT,// bf16 [B, 64, N] (scratch)
    float* __restrict__ s_out,      // f32 [B*N], = (X@a1)*log2(e)
    float* __restrict__ t_out)      // f32 [B*N], = (X@a2)*log2(e)
{
    __shared__ float Xl[4][16][UDIM + 1];

    const int tid  = threadIdx.x;
    const int wave = tid >> 6, lane = tid & 63;
    const int col  = lane & 15, quad = lane >> 4;
    const int i0   = (blockIdx.x * 4 + wave) * 16;

    f32x4 acc0 = {0,0,0,0}, acc1 = {0,0,0,0}, acc2 = {0,0,0,0}, acc3 = {0,0,0,0};
    const float* hrow = H + (size_t)(i0 + col) * FDIM + quad * 8;

    #pragma unroll
    for (int kb = 0; kb < FDIM; kb += 32) {
        f32x4 h0 = *(const f32x4*)(hrow + kb);       // A[m=lane&15][k=quad*8+j]
        f32x4 h1 = *(const f32x4*)(hrow + kb + 4);
        short8 afr, b0, b1, b2, b3;
        #pragma unroll
        for (int j = 0; j < 4; ++j) {
            afr[j]     = (short)f2bf(h0[j]);
            afr[4 + j] = (short)f2bf(h1[j]);
        }
        #pragma unroll
        for (int j = 0; j < 8; ++j) {                // W tiny, L1-hot
            int k = kb + quad * 8 + j;
            b0[j] = (short)f2bf(W[k * UDIM + col]);
            b1[j] = (short)f2bf(W[k * UDIM + 16 + col]);
            b2[j] = (short)f2bf(W[k * UDIM + 32 + col]);
            b3[j] = (short)f2bf(W[k * UDIM + 48 + col]);
        }
        acc0 = __builtin_amdgcn_mfma_f32_16x16x32_bf16(afr, b0, acc0, 0, 0, 0);
        acc1 = __builtin_amdgcn_mfma_f32_16x16x32_bf16(afr, b1, acc1, 0, 0, 0);
        acc2 = __builtin_amdgcn_mfma_f32_16x16x32_bf16(afr, b2, acc2, 0, 0, 0);
        acc3 = __builtin_amdgcn_mfma_f32_16x16x32_bf16(afr, b3, acc3, 0, 0, 0);
    }
    #pragma unroll
    for (int r = 0; r < 4; ++r) {   // C/D: col(u)=lane&15 (+16/group), row=quad*4+r
        Xl[wave][quad * 4 + r][col]      = acc0[r];
        Xl[wave][quad * 4 + r][16 + col] = acc1[r];
        Xl[wave][quad * 4 + r][32 + col] = acc2[r];
        Xl[wave][quad * 4 + r][48 + col] = acc3[r];
    }
    __syncthreads();

    const int b = i0 >> 12, n0 = i0 & (NTOK - 1);
    float ps = 0.f, pt = 0.f;
    #pragma unroll
    for (int ui = 0; ui < 16; ++ui) {
        int u = quad * 16 + ui;
        float x = Xl[wave][col][u];
        ps = fmaf(x, a1[u], ps);
        pt = fmaf(x, a2[u], pt);
    }
    ps += __shfl_xor(ps, 16, 64); ps += __shfl_xor(ps, 32, 64);
    pt += __shfl_xor(pt, 16, 64); pt += __shfl_xor(pt, 32, 64);
    const float LOG2E = 1.44269504f;
    if (quad == 0) s_out[i0 + col] = ps * LOG2E;   // exp2 domain
    if (quad == 1) t_out[i0 + col] = pt * LOG2E;

    #pragma unroll
    for (int ui = 0; ui < 16; ++ui) {
        int u = quad * 16 + ui;
        XT[(size_t)(b * UDIM + u) * NTOK + n0 + col] = f2bf(Xl[wave][col][u]);
    }
}

// ---------------- kernel 2: fused mask+softmax+PV ---------------------------
// grid 512 = 8 batches x 64 row-tiles-of-64 (b = bx&7), 4 waves/block.
// Wave w owns rows [i0+w*16, +16) across the FULL k range. A[64][BK] f32 and
// XT[64][BK] bf16 staged per chunk via coalesced block-cooperative loads into
// double-buffered padded LDS; one __syncthreads per chunk.
__global__ __launch_bounds__(256) void attn_kernel(
    const float* __restrict__ A,            // f32 [B, N, N] -- 512 MB stream
    const unsigned short* __restrict__ XT,  // bf16 [B, 64, N]
    const float* __restrict__ s_in,         // log2e-scaled
    const float* __restrict__ t_in,         // log2e-scaled
    float* __restrict__ out)                // f32 [B, N, 64]
{
    __shared__ __align__(16) float          As[2][64][BK + 4];  // 34.8 KB
    __shared__ __align__(16) unsigned short Xs[2][64][BK + 8];  // 18.4 KB

    const int tid  = threadIdx.x;
    const int wave = tid >> 6, lane = tid & 63;
    const int col  = lane & 15, quad = lane >> 4;
    const int b    = blockIdx.x & 7;
    const int i0   = (blockIdx.x >> 3) * 64;

    // staging assignment: A -> 4 instrs, each 16 rows x 256 B (4x256B segs/wave)
    //                     XT -> 2 instrs, each 32 rows x 128 B
    const int arow = tid >> 4, acol = (tid & 15) * 4;
    const int xrow = tid >> 3, xcol = (tid & 7) * 8;
    const float* agp = A + ((size_t)(b * NTOK + i0 + arow)) * NTOK + acol;
    const unsigned short* xgp = XT + ((size_t)(b * UDIM + xrow)) * NTOK + xcol;

    const float s_m = s_in[b * NTOK + i0 + wave * 16 + col];
    const float* tbase = t_in + b * NTOK;

    f32x4 acc[4];
    #pragma unroll
    for (int f = 0; f < 4; ++f) acc[f] = (f32x4){0,0,0,0};
    float den = 0.f;

    f32x4 av[4], xv[2];

    // prologue: stage chunk 0
    #pragma unroll
    for (int i = 0; i < 4; ++i)
        av[i] = __builtin_nontemporal_load((const f32x4*)(agp + (size_t)i * 16 * NTOK));
    #pragma unroll
    for (int i = 0; i < 2; ++i)
        xv[i] = *(const f32x4*)(xgp + (size_t)i * 32 * NTOK);
    #pragma unroll
    for (int i = 0; i < 4; ++i) *(f32x4*)&As[0][arow + i * 16][acol] = av[i];
    #pragma unroll
    for (int i = 0; i < 2; ++i) *(f32x4*)&Xs[0][xrow + i * 32][xcol] = xv[i];

    for (int c = 0; c < NTOK / BK; ++c) {
        const int buf = c & 1;
        if (c < NTOK / BK - 1) {         // issue next-chunk loads (land under compute)
            const float* ag = agp + (c + 1) * BK;
            const unsigned short* xg = xgp + (c + 1) * BK;
            #pragma unroll
            for (int i = 0; i < 4; ++i)
                av[i] = __builtin_nontemporal_load((const f32x4*)(ag + (size_t)i * 16 * NTOK));
            #pragma unroll
            for (int i = 0; i < 2; ++i)
                xv[i] = *(const f32x4*)(xg + (size_t)i * 32 * NTOK);
        }
        __syncthreads();                 // buf's ds_writes visible; prev reads done

        #pragma unroll
        for (int ks = 0; ks < 2; ++ks) {
            const float* ar = &As[buf][wave * 16 + col][ks * 32 + quad * 8];
            f32x4 a0 = *(const f32x4*)ar;
            f32x4 a1 = *(const f32x4*)(ar + 4);
            const float* tp = tbase + c * BK + ks * 32 + quad * 8;
            f32x4 t0 = *(const f32x4*)tp;
            f32x4 t1 = *(const f32x4*)(tp + 4);

            unsigned uw[8];
            #pragma unroll
            for (int j = 0; j < 4; ++j) {
                float l0 = s_m + t0[j], l1 = s_m + t1[j];
                float e0 = fmaxf(l0, 0.2f * l0);   // lrelu commutes with log2e>0
                float e1 = fmaxf(l1, 0.2f * l1);
                float w0 = __builtin_amdgcn_exp2f(e0) * a0[j];  // masked -> exact 0
                float w1 = __builtin_amdgcn_exp2f(e1) * a1[j];
                den += w0 + w1;
                uw[j]     = __float_as_uint(w0) + 0x8000u;  // round-half-up bf16
                uw[4 + j] = __float_as_uint(w1) + 0x8000u;
            }
            PackU p;   // pack hi16 pairs: afr[k]=w(k), k=quad*8+j
            p.u[0] = __builtin_amdgcn_perm(uw[1], uw[0], 0x07060302u);
            p.u[1] = __builtin_amdgcn_perm(uw[3], uw[2], 0x07060302u);
            p.u[2] = __builtin_amdgcn_perm(uw[5], uw[4], 0x07060302u);
            p.u[3] = __builtin_amdgcn_perm(uw[7], uw[6], 0x07060302u);

            short8 bf0 = *(const short8*)&Xs[buf][col]     [ks * 32 + quad * 8];
            short8 bf1 = *(const short8*)&Xs[buf][16 + col][ks * 32 + quad * 8];
            short8 bf2 = *(const short8*)&Xs[buf][32 + col][ks * 32 + quad * 8];
            short8 bf3 = *(const short8*)&Xs[buf][48 + col][ks * 32 + quad * 8];

            acc[0] = __builtin_amdgcn_mfma_f32_16x16x32_bf16(p.s, bf0, acc[0], 0, 0, 0);
            acc[1] = __builtin_amdgcn_mfma_f32_16x16x32_bf16(p.s, bf1, acc[1], 0, 0, 0);
            acc[2] = __builtin_amdgcn_mfma_f32_16x16x32_bf16(p.s, bf2, acc[2], 0, 0, 0);
            acc[3] = __builtin_amdgcn_mfma_f32_16x16x32_bf16(p.s, bf3, acc[3], 0, 0, 0);
        }

        if (c < NTOK / BK - 1) {         // write next chunk into the other buffer
            const int nb = buf ^ 1;
            #pragma unroll
            for (int i = 0; i < 4; ++i) *(f32x4*)&As[nb][arow + i * 16][acol] = av[i];
            #pragma unroll
            for (int i = 0; i < 2; ++i) *(f32x4*)&Xs[nb][xrow + i * 32][xcol] = xv[i];
        }
    }

    // epilogue: den lives at lane with col==row; gather, divide, relu, store
    den += __shfl_xor(den, 16, 64);
    den += __shfl_xor(den, 32, 64);      // full row-den at every quad, keyed by col
    #pragma unroll
    for (int r = 0; r < 4; ++r) {
        float dd = __shfl(den, quad * 4 + r, 64);     // den of D-row quad*4+r
        const int row = i0 + wave * 16 + quad * 4 + r;
        #pragma unroll
        for (int f = 0; f < 4; ++f) {
            float o = fmaxf(acc[f][r] / dd, 0.f);
            __builtin_nontemporal_store(o, &out[(size_t)(b * NTOK + row) * UDIM + f * 16 + col]);
        }
    }
}

extern "C" void kernel_launch(void* const* d_in, const int* in_sizes, int n_in,
                              void* d_out, int out_size, void* d_ws, size_t ws_size,
                              hipStream_t stream) {
    const float* H  = (const float*)d_in[0];
    const float* A  = (const float*)d_in[1];
    const float* W  = (const float*)d_in[2];
    const float* a1 = (const float*)d_in[3];
    const float* a2 = (const float*)d_in[4];
    float* out = (float*)d_out;

    char* ws = (char*)d_ws;
    unsigned short* XT = (unsigned short*)ws;                               // 4 MB bf16
    size_t off = (size_t)BATCH * UDIM * NTOK * 2;
    float* s = (float*)(ws + off);                                          // 128 KB
    off += (size_t)BATCH * NTOK * 4;
    float* t = (float*)(ws + off);                                          // 128 KB

    prep_kernel<<<512, 256, 0, stream>>>(H, W, a1, a2, XT, s, t);
    attn_kernel<<<512, 256, 0, stream>>>(A, XT, s, t, out);
}